// Round 3
// baseline (523.346 us; speedup 1.0000x reference)
//
#include <hip/hip_runtime.h>
#include <stdint.h>

#define B_ROWS 512
#define N_FEATS 100000
#define N_PAD 100352      // 1568 n-strips of 64 = 8 XCDs x 196
#define D_DIM 512
#define C_CLS 1854
#define TOPK 10
#define CAP 512
#define THR 0.139f

typedef __bf16 bf16x8 __attribute__((ext_vector_type(8)));
typedef float f32x4 __attribute__((ext_vector_type(4)));

__device__ __forceinline__ unsigned short f32_bf16_rne(float f) {
    unsigned int u = __float_as_uint(f);
    unsigned int r = (u + 0x7FFFu + ((u >> 16) & 1u)) >> 16;
    return (unsigned short)r;
}

// Kernel A: normalize y_pred rows -> bf16 (RNE), zero per-row candidate counters.
__global__ void norm_rows(const float* __restrict__ yp,
                          unsigned short* __restrict__ ypb,
                          int* __restrict__ counts) {
    int r = blockIdx.x;
    int l = threadIdx.x;  // 64 threads = 1 wave
    const float* row = yp + r * D_DIM;
    float v[8];
    float ss = 0.f;
#pragma unroll
    for (int i = 0; i < 8; ++i) { v[i] = row[l + i * 64]; ss += v[i] * v[i]; }
#pragma unroll
    for (int off = 32; off >= 1; off >>= 1) ss += __shfl_down(ss, off);
    ss = __shfl(ss, 0);
    float rn = rsqrtf(ss);
#pragma unroll
    for (int i = 0; i < 8; ++i)
        ypb[r * D_DIM + l + i * 64] = f32_bf16_rne(v[i] * rn);
    if (l == 0) counts[r] = 0;
}

// Kernel B (FUSED, barrier-free): direct-to-register 64x64-per-wave MFMA GEMM.
// R2 post-mortem: barrier-phased LDS pipelines convoy all waves onto one
// waitcnt -> latency-bound at 771 GB/s. This version has NO LDS, NO barriers:
// each wave streams its own A (bf16, L2-hot) and B (fp32, cvt in-register)
// fragments straight from global, like the full-BW cvt_feats streamer did.
//  - block = 4 waves on the SAME 64-col n-strip (m-halves 0..255 / 256..511)
//    -> B slice read once per block (L1 dedups the 4-wave reuse).
//  - grid = 1568 n-strips x 2 m-halves, bijective XCD swizzle (1568%8==0):
//    each XCD streams a contiguous 196-strip feats range -> L2 locality.
//  - A-frag loads: 16 rows x 64B full lines (kk*2 is 64-aligned). B-frag:
//    2 float4/lane, row-pairs fully covered -> 100% sector efficiency.
//  - occupancy: 0 LDS, VGPR-capped -> 12 waves/CU (launch_bounds(256,3)),
//    each with ~12 loads in flight, free-running (no convoys).
// Epilogue: threshold + append candidates (C/D layout m89/m91-verified).
__launch_bounds__(256, 3)
__global__ void gemm_thresh(const unsigned short* __restrict__ A,
                            const float* __restrict__ Bf,
                            int* __restrict__ counts, int* __restrict__ cand) {
    const int t = threadIdx.x;
    const int bid = blockIdx.x;
    const int xcd = bid & 7, slot = bid >> 3;      // 392 slots per XCD
    const int m0 = (slot & 1) * 256;               // m-half
    const int n0 = (xcd * 196 + (slot >> 1)) * 64; // n-strip base (64 cols)
    const int w = t >> 6, lane = t & 63;
    const int r16 = lane & 15, kg = lane >> 4;
    const int rw = m0 + w * 64;                    // wave's 64-row A range

    const unsigned short* Ap = A + (rw + r16) * D_DIM + kg * 8;
    const float* Bp[4];
    bool g[4];
#pragma unroll
    for (int ni = 0; ni < 4; ++ni) {
        int nr = n0 + ni * 16 + r16;
        g[ni] = (nr < N_FEATS);
        Bp[ni] = Bf + (long long)(g[ni] ? nr : 0) * D_DIM + kg * 8;
    }

    f32x4 acc[4][4] = {};
#pragma unroll 2
    for (int kk = 0; kk < D_DIM; kk += 32) {
        bf16x8 aF[4], bF[4];
#pragma unroll
        for (int mi = 0; mi < 4; ++mi)
            aF[mi] = *(const bf16x8*)(Ap + mi * 16 * D_DIM + kk);
#pragma unroll
        for (int ni = 0; ni < 4; ++ni) {
            const float4* p = (const float4*)(Bp[ni] + kk);
            float4 lo = p[0], hi = p[1];
            if (!g[ni]) { lo = make_float4(0.f, 0.f, 0.f, 0.f); hi = lo; }
            bF[ni][0] = (__bf16)lo.x; bF[ni][1] = (__bf16)lo.y;
            bF[ni][2] = (__bf16)lo.z; bF[ni][3] = (__bf16)lo.w;
            bF[ni][4] = (__bf16)hi.x; bF[ni][5] = (__bf16)hi.y;
            bF[ni][6] = (__bf16)hi.z; bF[ni][7] = (__bf16)hi.w;
        }
#pragma unroll
        for (int mi = 0; mi < 4; ++mi)
#pragma unroll
            for (int ni = 0; ni < 4; ++ni)
                acc[mi][ni] = __builtin_amdgcn_mfma_f32_16x16x32_bf16(aF[mi], bF[ni], acc[mi][ni], 0, 0, 0);
    }

    // Epilogue: C/D layout col=lane&15, row=(lane>>4)*4+reg.
#pragma unroll
    for (int mi = 0; mi < 4; ++mi) {
        int rowb = rw + mi * 16 + kg * 4;
#pragma unroll
        for (int ni = 0; ni < 4; ++ni) {
            int col = n0 + ni * 16 + r16;
#pragma unroll
            for (int r = 0; r < 4; ++r) {
                float v = acc[mi][ni][r];
                if (v > THR && col < N_FEATS) {
                    int row = rowb + r;
                    int idx = atomicAdd(&counts[row], 1);
                    if (idx < CAP) cand[row * CAP + idx] = col;
                }
            }
        }
    }
}

// Kernel D: exact fp64 rescoring of candidates, top-10 (ties -> lower col),
// zero + scatter the output row. 512 threads = 8 waves.
__global__ void rescore_topk(const float* __restrict__ yp, const float* __restrict__ feats,
                             const int* __restrict__ y, const int* __restrict__ counts,
                             const int* __restrict__ cand, float* __restrict__ out) {
    __shared__ float sy[D_DIM];
    __shared__ double sc[CAP];
    __shared__ int scol[CAP];
    __shared__ int stop[TOPK];
    int b = blockIdx.x, t = threadIdx.x;
    sy[t] = yp[b * D_DIM + t];
    int cnt = counts[b];
    if (cnt > CAP) cnt = CAP;
    __syncthreads();
    int w = t >> 6, lane = t & 63;
    for (int c = w; c < cnt; c += 8) {
        int col = cand[b * CAP + c];
        const float* fr = feats + (long long)col * D_DIM;
        double s = 0.0;
#pragma unroll
        for (int i = 0; i < 8; ++i) {
            int e = lane + i * 64;
            s += (double)sy[e] * (double)fr[e];
        }
#pragma unroll
        for (int off = 32; off >= 1; off >>= 1) s += __shfl_down(s, off);
        if (lane == 0) { sc[c] = s; scol[c] = col; }
    }
    __syncthreads();
    if (w == 0) {
        double ls[8];
        int lc[8];
#pragma unroll
        for (int i = 0; i < 8; ++i) {
            int c = lane + i * 64;
            if (c < cnt) { ls[i] = sc[c]; lc[i] = scol[c]; }
            else         { ls[i] = -1e300; lc[i] = 0x7fffffff; }
        }
        for (int k = 0; k < TOPK; ++k) {
            double bs = -1e300;
            int bc = 0x7fffffff, bi = -1, bl = lane;
#pragma unroll
            for (int i = 0; i < 8; ++i) {
                if (ls[i] > bs || (ls[i] == bs && lc[i] < bc)) { bs = ls[i]; bc = lc[i]; bi = i; }
            }
            for (int off = 32; off >= 1; off >>= 1) {
                double os = __shfl_down(bs, off);
                int oc = __shfl_down(bc, off);
                int ol = __shfl_down(bl, off);
                int oi = __shfl_down(bi, off);
                if (os > bs || (os == bs && oc < bc)) { bs = os; bc = oc; bl = ol; bi = oi; }
            }
            int wl = __shfl(bl, 0);
            int wi = __shfl(bi, 0);
            int wc = __shfl(bc, 0);
            if (lane == 0) stop[k] = (wc != 0x7fffffff) ? wc : -1;
            if (lane == wl && wi >= 0) ls[wi] = -1e300;
        }
    }
    __syncthreads();
    for (int i = t; i < C_CLS; i += 512) out[b * C_CLS + i] = 0.0f;
    __syncthreads();
    if (t < TOPK) {
        int col = stop[t];
        if (col >= 0) out[b * C_CLS + y[col]] = 1.0f;
    }
}

extern "C" void kernel_launch(void* const* d_in, const int* in_sizes, int n_in,
                              void* d_out, int out_size, void* d_ws, size_t ws_size,
                              hipStream_t stream) {
    const float* y_pred = (const float*)d_in[0];
    const float* feats  = (const float*)d_in[1];
    const int*   y      = (const int*)d_in[2];
    float* out = (float*)d_out;

    char* ws = (char*)d_ws;
    unsigned short* ypb = (unsigned short*)ws;          // 512 KB
    size_t off = (size_t)B_ROWS * D_DIM * 2;
    int* counts = (int*)(ws + off);                     // 2 KB
    off += (size_t)B_ROWS * 4;
    int* cand = (int*)(ws + off);                       // 1 MB

    norm_rows<<<dim3(B_ROWS), dim3(64), 0, stream>>>(y_pred, ypb, counts);
    gemm_thresh<<<dim3((N_PAD / 64) * 2), dim3(256), 0, stream>>>(ypb, feats, counts, cand);
    rescore_topk<<<dim3(B_ROWS), dim3(512), 0, stream>>>(y_pred, feats, y, counts, cand, out);
}

// Round 4
// 410.514 us; speedup vs baseline: 1.2749x; 1.2749x over previous
//
#include <hip/hip_runtime.h>
#include <stdint.h>

#define B_ROWS 512
#define N_FEATS 100000
#define N_PAD 100352      // 1568 n-strips of 64 = 8 XCDs x 196
#define D_DIM 512
#define C_CLS 1854
#define TOPK 10
#define CAP 512
#define THR 0.139f

typedef __bf16 bf16x8 __attribute__((ext_vector_type(8)));
typedef float f32x4 __attribute__((ext_vector_type(4)));

__device__ __forceinline__ unsigned short f32_bf16_rne(float f) {
    unsigned int u = __float_as_uint(f);
    unsigned int r = (u + 0x7FFFu + ((u >> 16) & 1u)) >> 16;
    return (unsigned short)r;
}

// Kernel A: normalize y_pred rows -> bf16 (RNE), zero per-row candidate counters.
__global__ void norm_rows(const float* __restrict__ yp,
                          unsigned short* __restrict__ ypb,
                          int* __restrict__ counts) {
    int r = blockIdx.x;
    int l = threadIdx.x;  // 64 threads = 1 wave
    const float* row = yp + r * D_DIM;
    float v[8];
    float ss = 0.f;
#pragma unroll
    for (int i = 0; i < 8; ++i) { v[i] = row[l + i * 64]; ss += v[i] * v[i]; }
#pragma unroll
    for (int off = 32; off >= 1; off >>= 1) ss += __shfl_down(ss, off);
    ss = __shfl(ss, 0);
    float rn = rsqrtf(ss);
#pragma unroll
    for (int i = 0; i < 8; ++i)
        ypb[r * D_DIM + l + i * 64] = f32_bf16_rne(v[i] * rn);
    if (l == 0) counts[r] = 0;
}

// Kernel B (FUSED, stream-stage): per-block 64-col n-strip, FULL-K staging.
// Empirical law from R0-R3: only byte-linear wave footprints reach streaming
// HBM BW (5.5+ TB/s); row-strided 64-128B segment patterns cap at <=1.8 TB/s.
// A feats row (2KB fp32) == full K, so we stage the whole 64-row strip in ONE
// linear pass: global addr = strip_base + g*16B, g = i*512+t -> every load
// instruction covers 1KB contiguous. fp32->bf16 cvt in regs, XOR-swizzled
// ds_write. ONE __syncthreads, then a barrier-free K-loop:
//   - 8 waves x (64m x 64n): all 512 m-rows covered -> B fetched from HBM once.
//   - A-frags direct from global (512KB bf16, L2-resident per XCD).
//   - B-frags from LDS, chunk^(row&7) swizzle -> uniform 32-bank spread.
// 64KB LDS -> 2 blocks/CU (16 waves): one block stages (HBM) while the other
// computes (MFMA+L2) -> phases overlap without intra-block pipelining.
// Grid 1568 = 8 XCDs x 196 strips; bid&7 = XCD -> each XCD streams a
// contiguous 196-strip feats range, A stays hot in its L2.
__launch_bounds__(512, 4)
__global__ void gemm_thresh(const unsigned short* __restrict__ A,
                            const float* __restrict__ Bf,
                            int* __restrict__ counts, int* __restrict__ cand) {
    __shared__ unsigned short lB[64 * 512];  // 64 KB, [row][512 bf16] swizzled
    const int t = threadIdx.x;
    const int bid = blockIdx.x;
    const int xcd = bid & 7, s = bid >> 3;
    const int n0 = (xcd * 196 + s) * 64;     // strip base (64 feats rows)
    const int w = t >> 6, lane = t & 63;
    const int r16 = lane & 15, kg = lane >> 4;
    const int rw = w * 64;                   // wave's 64 m-rows

    // ---- stage: 128KB fp32 strip, byte-linear; cvt -> swizzled LDS ----
    {
        const float4* base = (const float4*)Bf + (long long)n0 * 128;
        float4 st[16];
#pragma unroll
        for (int i = 0; i < 16; ++i) {
            int g = i * 512 + t;             // float4 index in strip
            bool ok = (n0 + (g >> 7)) < N_FEATS;
            st[i] = ok ? base[g] : make_float4(0.f, 0.f, 0.f, 0.f);
        }
#pragma unroll
        for (int i = 0; i < 16; ++i) {
            int g = i * 512 + t;
            int r = g >> 7, q = g & 127;     // row, 16B-fp32 chunk in row
            uint2 d;
            d.x = (unsigned)f32_bf16_rne(st[i].x) | ((unsigned)f32_bf16_rne(st[i].y) << 16);
            d.y = (unsigned)f32_bf16_rne(st[i].z) | ((unsigned)f32_bf16_rne(st[i].w) << 16);
            // bf16 16B-chunk c = q>>1 stored at c^(r&7); q&1 selects 8B half
            int ush = r * 512 + ((((q >> 1) ^ (r & 7)) << 3) | ((q & 1) << 2));
            *(uint2*)&lB[ush] = d;
        }
    }
    __syncthreads();

    // ---- barrier-free K-loop: A from global (L2-hot), B from LDS ----
    const unsigned short* Ap = A + (rw + r16) * D_DIM + kg * 8;
    f32x4 acc[4][4] = {};
#pragma unroll 2
    for (int kk = 0; kk < D_DIM; kk += 32) {
        bf16x8 aF[4], bF[4];
#pragma unroll
        for (int mi = 0; mi < 4; ++mi)
            aF[mi] = *(const bf16x8*)(Ap + mi * 16 * D_DIM + kk);
        int c0 = (kk >> 3) + kg;             // 16B-chunk index within row
#pragma unroll
        for (int ni = 0; ni < 4; ++ni) {
            int row = ni * 16 + r16;
            bF[ni] = *(const bf16x8*)&lB[row * 512 + ((c0 ^ (row & 7)) << 3)];
        }
#pragma unroll
        for (int mi = 0; mi < 4; ++mi)
#pragma unroll
            for (int ni = 0; ni < 4; ++ni)
                acc[mi][ni] = __builtin_amdgcn_mfma_f32_16x16x32_bf16(aF[mi], bF[ni], acc[mi][ni], 0, 0, 0);
    }

    // Epilogue: C/D layout col=lane&15, row=(lane>>4)*4+reg (m89/m91-verified).
#pragma unroll
    for (int mi = 0; mi < 4; ++mi) {
        int rowb = rw + mi * 16 + kg * 4;
#pragma unroll
        for (int ni = 0; ni < 4; ++ni) {
            int col = n0 + ni * 16 + r16;
#pragma unroll
            for (int r = 0; r < 4; ++r) {
                float v = acc[mi][ni][r];
                if (v > THR && col < N_FEATS) {
                    int row = rowb + r;
                    int idx = atomicAdd(&counts[row], 1);
                    if (idx < CAP) cand[row * CAP + idx] = col;
                }
            }
        }
    }
}

// Kernel D: exact fp64 rescoring of candidates, top-10 (ties -> lower col),
// zero + scatter the output row. 512 threads = 8 waves.
__global__ void rescore_topk(const float* __restrict__ yp, const float* __restrict__ feats,
                             const int* __restrict__ y, const int* __restrict__ counts,
                             const int* __restrict__ cand, float* __restrict__ out) {
    __shared__ float sy[D_DIM];
    __shared__ double sc[CAP];
    __shared__ int scol[CAP];
    __shared__ int stop[TOPK];
    int b = blockIdx.x, t = threadIdx.x;
    sy[t] = yp[b * D_DIM + t];
    int cnt = counts[b];
    if (cnt > CAP) cnt = CAP;
    __syncthreads();
    int w = t >> 6, lane = t & 63;
    for (int c = w; c < cnt; c += 8) {
        int col = cand[b * CAP + c];
        const float* fr = feats + (long long)col * D_DIM;
        double s = 0.0;
#pragma unroll
        for (int i = 0; i < 8; ++i) {
            int e = lane + i * 64;
            s += (double)sy[e] * (double)fr[e];
        }
#pragma unroll
        for (int off = 32; off >= 1; off >>= 1) s += __shfl_down(s, off);
        if (lane == 0) { sc[c] = s; scol[c] = col; }
    }
    __syncthreads();
    if (w == 0) {
        double ls[8];
        int lc[8];
#pragma unroll
        for (int i = 0; i < 8; ++i) {
            int c = lane + i * 64;
            if (c < cnt) { ls[i] = sc[c]; lc[i] = scol[c]; }
            else         { ls[i] = -1e300; lc[i] = 0x7fffffff; }
        }
        for (int k = 0; k < TOPK; ++k) {
            double bs = -1e300;
            int bc = 0x7fffffff, bi = -1, bl = lane;
#pragma unroll
            for (int i = 0; i < 8; ++i) {
                if (ls[i] > bs || (ls[i] == bs && lc[i] < bc)) { bs = ls[i]; bc = lc[i]; bi = i; }
            }
            for (int off = 32; off >= 1; off >>= 1) {
                double os = __shfl_down(bs, off);
                int oc = __shfl_down(bc, off);
                int ol = __shfl_down(bl, off);
                int oi = __shfl_down(bi, off);
                if (os > bs || (os == bs && oc < bc)) { bs = os; bc = oc; bl = ol; bi = oi; }
            }
            int wl = __shfl(bl, 0);
            int wi = __shfl(bi, 0);
            int wc = __shfl(bc, 0);
            if (lane == 0) stop[k] = (wc != 0x7fffffff) ? wc : -1;
            if (lane == wl && wi >= 0) ls[wi] = -1e300;
        }
    }
    __syncthreads();
    for (int i = t; i < C_CLS; i += 512) out[b * C_CLS + i] = 0.0f;
    __syncthreads();
    if (t < TOPK) {
        int col = stop[t];
        if (col >= 0) out[b * C_CLS + y[col]] = 1.0f;
    }
}

extern "C" void kernel_launch(void* const* d_in, const int* in_sizes, int n_in,
                              void* d_out, int out_size, void* d_ws, size_t ws_size,
                              hipStream_t stream) {
    const float* y_pred = (const float*)d_in[0];
    const float* feats  = (const float*)d_in[1];
    const int*   y      = (const int*)d_in[2];
    float* out = (float*)d_out;

    char* ws = (char*)d_ws;
    unsigned short* ypb = (unsigned short*)ws;          // 512 KB
    size_t off = (size_t)B_ROWS * D_DIM * 2;
    int* counts = (int*)(ws + off);                     // 2 KB
    off += (size_t)B_ROWS * 4;
    int* cand = (int*)(ws + off);                       // 1 MB

    norm_rows<<<dim3(B_ROWS), dim3(64), 0, stream>>>(y_pred, ypb, counts);
    gemm_thresh<<<dim3(N_PAD / 64), dim3(512), 0, stream>>>(ypb, feats, counts, cand);
    rescore_topk<<<dim3(B_ROWS), dim3(512), 0, stream>>>(y_pred, feats, y, counts, cand, out);
}